// Round 1
// baseline (485.143 us; speedup 1.0000x reference)
//
#include <hip/hip_runtime.h>
#include <hip/hip_bf16.h>
#include <math.h>

// Problem constants (B=2, C=256, H=W=128, N=16384, SR=4, HEADS=8, hd=32, M=1024)
#define EPSF 1e-5f
#define SCALE 0.17677669529663687f  // 1/sqrt(32)

typedef __bf16 bf16x8 __attribute__((ext_vector_type(8)));
typedef float f32x4 __attribute__((ext_vector_type(4)));

// Fragment-major layouts (MFMA 16x16x32, A/B frag = [row/col ln<16][k=quad*8+j]):
//   xTf : x^T  [b][n_tile(1024)][cc(8)][lane(64)][j(8)]
//   wqf : w_q  [o_tile(16)][cc(8)][lane][j]
//   Pbf : P    [b][m_tile(64)][cc(128)][lane][j]
//   wsrf: w_sr [o_tile(16)][cc(128)][lane][j]
//   kkbh: k    [b][h(8)][m(1024)][d(32)]
//
// Pipeline (4 launches):
//   K1 k_prep : weight conv + zero(v,ssg,cnt) || im2col          (1120 blocks)
//   K2 k_cx   : conv1f (MFMA-bound) || xT transpose + v (BW)     (1024 blocks)
//   K3 k_kmat2: k GEMM + A/B0 prep                               (130 blocks)
//   K4 k_sc   : q + scores + fused epilogue via atomic counter   (2048 blocks)

// ---------------------------------------------------------------------------
// K1: weight conversions + zeroing + im2col.  grid = 608 + 512 = 1120.
__global__ __launch_bounds__(256) void k_prep(const float* __restrict__ wq,
                                              const float* __restrict__ wk,
                                              const float* __restrict__ wsr,
                                              const float* __restrict__ x,
                                              __bf16* __restrict__ wqf,
                                              __bf16* __restrict__ wkb,
                                              __bf16* __restrict__ wsrf,
                                              __bf16* __restrict__ Pbf,
                                              float* __restrict__ v,
                                              float* __restrict__ ssg,
                                              int* __restrict__ cnt) {
    const int bi = blockIdx.x, t = threadIdx.x;
    if (bi >= 608) {
        // ---- im2col (pure staging; v moved to K2's xT path -> no barriers) ----
        const int bid = bi - 608;
        const int b = bid >> 8, hm = (bid >> 3) & 31, ccg = bid & 7;
        const int wm = t >> 3, c8 = t & 7;
        const int mtile = (hm << 1) + (wm >> 4);
        const int ln = wm & 15;
#pragma unroll
        for (int cci = 0; cci < 4; ++cci) {
            const int c = (ccg << 5) + (cci << 3) + c8;
            const float* src = x + ((size_t)(b * 256 + c) << 14) + (hm << 9) + (wm << 2);
            bf16x8 o0, o1;
#pragma unroll
            for (int p = 0; p < 2; ++p) {
                float4 vv = *(const float4*)&src[p << 7];
                o0[p * 4 + 0] = (__bf16)vv.x; o0[p * 4 + 1] = (__bf16)vv.y;
                o0[p * 4 + 2] = (__bf16)vv.z; o0[p * 4 + 3] = (__bf16)vv.w;
            }
#pragma unroll
            for (int p = 0; p < 2; ++p) {
                float4 vv = *(const float4*)&src[(p + 2) << 7];
                o1[p * 4 + 0] = (__bf16)vv.x; o1[p * 4 + 1] = (__bf16)vv.y;
                o1[p * 4 + 2] = (__bf16)vv.z; o1[p * 4 + 3] = (__bf16)vv.w;
            }
            size_t d0 = (((((size_t)(b * 64 + mtile) << 7) + (c >> 1)) << 6) +
                         (((c & 1) << 1) << 4) + ln) << 3;
            *(bf16x8*)&Pbf[d0] = o0;
            *(bf16x8*)&Pbf[d0 + 128] = o1;
        }
        return;
    }
    if (bi >= 576) {  // zero ssg (2*16384 f) + cnt (512 i)
        if (bi == 576 && t < 128) *(int4*)&cnt[t << 2] = make_int4(0, 0, 0, 0);
        int e = (bi - 576) * 256 + t;
        *(float4*)&ssg[e << 2] = make_float4(0.f, 0.f, 0.f, 0.f);
        return;
    }
    if (bi < 32) {
        if (bi == 0) { v[t] = 0.f; v[256 + t] = 0.f; }
        int tt = bi * 256 + t;
        int o = tt >> 5, chunk = tt & 31;
        float4 v0 = *(const float4*)&wq[o * 256 + (chunk << 3)];
        float4 v1 = *(const float4*)&wq[o * 256 + (chunk << 3) + 4];
        bf16x8 p;
        p[0] = (__bf16)v0.x; p[1] = (__bf16)v0.y; p[2] = (__bf16)v0.z; p[3] = (__bf16)v0.w;
        p[4] = (__bf16)v1.x; p[5] = (__bf16)v1.y; p[6] = (__bf16)v1.z; p[7] = (__bf16)v1.w;
        int cc = chunk >> 2, quad = chunk & 3;
        *(bf16x8*)&wqf[(((((o >> 4) << 3) + cc) << 6) + (quad << 4) + (o & 15)) << 3] = p;
    } else if (bi < 64) {
        int e = (bi - 32) * 256 + t;
        float4 v0 = *(const float4*)&wk[e << 3];
        float4 v1 = *(const float4*)&wk[(e << 3) + 4];
        bf16x8 p;
        p[0] = (__bf16)(v0.x * SCALE); p[1] = (__bf16)(v0.y * SCALE);
        p[2] = (__bf16)(v0.z * SCALE); p[3] = (__bf16)(v0.w * SCALE);
        p[4] = (__bf16)(v1.x * SCALE); p[5] = (__bf16)(v1.y * SCALE);
        p[6] = (__bf16)(v1.z * SCALE); p[7] = (__bf16)(v1.w * SCALE);
        *(bf16x8*)&wkb[e << 3] = p;
    } else {
        int tt = (bi - 64) * 256 + t;
        int o = tt >> 9, chunk = tt & 511;
        float4 v0 = *(const float4*)&wsr[o * 4096 + (chunk << 3)];
        float4 v1 = *(const float4*)&wsr[o * 4096 + (chunk << 3) + 4];
        bf16x8 p;
        p[0] = (__bf16)v0.x; p[1] = (__bf16)v0.y; p[2] = (__bf16)v0.z; p[3] = (__bf16)v0.w;
        p[4] = (__bf16)v1.x; p[5] = (__bf16)v1.y; p[6] = (__bf16)v1.z; p[7] = (__bf16)v1.w;
        int cc = chunk >> 2, quad = chunk & 3;
        *(bf16x8*)&wsrf[(((((o >> 4) << 7) + cc) << 6) + (quad << 4) + (o & 15)) << 3] = p;
    }
}

// ---------------------------------------------------------------------------
// K2: blocks 0..511 = conv1f (MFMA GEMM + BN, compute-bound);
//     blocks 512..1023 = xT transpose + v column-sums (BW-bound).
// Complementary pipes overlap within one launch.
__global__ __launch_bounds__(256) void k_cx(const __bf16* __restrict__ Pbf,
                                            const __bf16* __restrict__ wsrf,
                                            const float* __restrict__ sg,
                                            const float* __restrict__ sb,
                                            const float* __restrict__ smn,
                                            const float* __restrict__ svar,
                                            __bf16* __restrict__ xrb,
                                            const float* __restrict__ x,
                                            __bf16* __restrict__ xTf,
                                            float* __restrict__ v) {
    const int t = threadIdx.x, bid0 = blockIdx.x;
    if (bid0 < 512) {
        // ---- conv1f ----
        const int b = bid0 & 1, mt = (bid0 >> 1) & 63, og = bid0 >> 7;
        const int w = t >> 6, lane = t & 63, ln = lane & 15, quad = lane >> 4;
        f32x4 acc = (f32x4){0.f, 0.f, 0.f, 0.f};
        const __bf16* pa = Pbf + ((size_t)(b * 64 + mt) << 16) + (lane << 3);
        const __bf16* pbm = wsrf + ((size_t)(og * 4 + w) << 16) + (lane << 3);
#pragma unroll 8
        for (int cc = 0; cc < 128; ++cc) {
            bf16x8 af = *(const bf16x8*)&pa[cc << 9];
            bf16x8 bf = *(const bf16x8*)&pbm[cc << 9];
            acc = __builtin_amdgcn_mfma_f32_16x16x32_bf16(af, bf, acc, 0, 0, 0);
        }
        const int o = (og << 6) + (w << 4) + ln;
        float inv = sg[o] / sqrtf(svar[o] + EPSF);
        float mn = smn[o], bt = sb[o];
#pragma unroll
        for (int r = 0; r < 4; ++r) {
            int m = (mt << 4) + (quad << 2) + r;
            xrb[(((size_t)b << 10) + m) * 256 + o] = (__bf16)((acc[r] - mn) * inv + bt);
        }
    } else {
        // ---- xT + v ----
        __shared__ float ts[32 * 68];
        __shared__ float sv[256];
        const int bid = bid0 - 512;
        const int b = bid >> 8, n0 = (bid & 255) << 6;
        const int nl = t >> 2;
        const int ch = (t & 3) << 3;
        const int n = n0 + nl;
        const int ntile = n >> 4, ln = n & 15, quad = ch >> 3;
        const int cl = t >> 3;
        const int n8 = (t & 7) << 3;
        sv[t] = 0.f;
        for (int s8 = 0; s8 < 8; ++s8) {
            const int c0 = s8 << 5;
            __syncthreads();
            {
                const float* src = &x[((size_t)(b * 256 + c0 + cl) << 14) + n0 + n8];
                float4 a0 = *(const float4*)&src[0];
                float4 a1 = *(const float4*)&src[4];
                *(float4*)&ts[cl * 68 + n8] = a0;
                *(float4*)&ts[cl * 68 + n8 + 4] = a1;
                atomicAdd(&sv[c0 + cl],
                          a0.x + a0.y + a0.z + a0.w + a1.x + a1.y + a1.z + a1.w);
            }
            __syncthreads();
            bf16x8 p;
#pragma unroll
            for (int j = 0; j < 8; ++j) p[j] = (__bf16)ts[(ch + j) * 68 + nl];
            *(bf16x8*)&xTf[(((((size_t)(b * 1024 + ntile) << 3) + s8) << 6) +
                            (quad << 4) + ln) << 3] = p;
        }
        __syncthreads();
        atomicAdd(&v[b * 256 + t], sv[t]);
    }
}

// ---------------------------------------------------------------------------
// K3: MFMA GEMM kkbh = xrb x wkb (blocks 0..127) + k_ab work (128..129).
__global__ __launch_bounds__(256) void k_kmat2(const __bf16* __restrict__ xrb,
                                               const __bf16* __restrict__ wkb,
                                               __bf16* __restrict__ kkbh,
                                               const float* __restrict__ v,
                                               const float* __restrict__ wproj,
                                               const float* __restrict__ pg,
                                               const float* __restrict__ pb,
                                               const float* __restrict__ pm,
                                               const float* __restrict__ pvar,
                                               float* __restrict__ A,
                                               float* __restrict__ B0) {
    const int t = threadIdx.x, bid = blockIdx.x;
    if (bid >= 128) {
        // ---- k_ab ----
        __shared__ float vl[256];
        int b = bid - 128;
        vl[t] = v[b * 256 + t] * (1.0f / 16384.0f);
        __syncthreads();
        const float* wr = wproj + t * 256;
        float s = 0.f;
#pragma unroll 8
        for (int c = 0; c < 256; c += 4) {
            float4 w4 = *(const float4*)&wr[c];
            s += w4.x * vl[c] + w4.y * vl[c + 1] + w4.z * vl[c + 2] + w4.w * vl[c + 3];
        }
        float inv = pg[t] / sqrtf(pvar[t] + EPSF);
        A[b * 256 + t] = s * inv;
        if (b == 0) B0[t] = pb[t] - pm[t] * inv;
        return;
    }
    const int b = bid >> 6, mt = bid & 63;
    const int w = t >> 6, lane = t & 63, ln = lane & 15, quad = lane >> 4;
    f32x4 acc[4];
#pragma unroll
    for (int ot = 0; ot < 4; ++ot) acc[ot] = (f32x4){0.f, 0.f, 0.f, 0.f};
    const __bf16* pa = xrb + ((((size_t)b << 10) + (mt << 4) + ln) << 8) + (quad << 3);
    const __bf16* pbm = wkb + (((w << 6) + ln) << 8) + (quad << 3);
#pragma unroll
    for (int cc = 0; cc < 8; ++cc) {
        const int cb = cc << 5;
        bf16x8 af = *(const bf16x8*)&pa[cb];
        bf16x8 bfr[4];
#pragma unroll
        for (int ot = 0; ot < 4; ++ot) bfr[ot] = *(const bf16x8*)&pbm[(ot << 12) + cb];
#pragma unroll
        for (int ot = 0; ot < 4; ++ot)
            acc[ot] = __builtin_amdgcn_mfma_f32_16x16x32_bf16(af, bfr[ot], acc[ot], 0, 0, 0);
    }
#pragma unroll
    for (int ot = 0; ot < 4; ++ot)
#pragma unroll
        for (int r = 0; r < 4; ++r) {
            int m = (mt << 4) + (quad << 2) + r;
            int h = (w << 1) + (ot >> 1);
            int d = ((ot & 1) << 4) + ln;
            kkbh[(((size_t)(b * 8 + h)) << 15) + (m << 5) + d] = (__bf16)acc[ot][r];
        }
}

// ---------------------------------------------------------------------------
// K4: q + scores + fused epilogue.  grid = b(2) x nchunk(256) x hp(4) = 2048.
// Last-arriving of the 4 hp blocks per (b,nchunk) writes the output slice
// (device-scope counter; output write overlaps other blocks' compute).
__global__ __launch_bounds__(256) void k_sc(const __bf16* __restrict__ xTf,
                                            const __bf16* __restrict__ wqf,
                                            const __bf16* __restrict__ kkbh,
                                            float* __restrict__ ssg,
                                            int* __restrict__ cnt,
                                            const float* __restrict__ A,
                                            const float* __restrict__ B0,
                                            float* __restrict__ out) {
    __shared__ __align__(16) __bf16 qs[64 * 72];
    __shared__ float smax[512];  // [w][hl][n64]
    __shared__ int sdone;
    const int t = threadIdx.x;
    const int w = t >> 6;
    const int lane = t & 63;
    const int ln = lane & 15;
    const int quad = lane >> 4;
    const int bx = blockIdx.x;
    const int hp = bx & 3;
    const int nch = (bx >> 2) & 255;
    const int n0 = nch << 6;
    const int b = bx >> 10;

    // ---------------- q phase: wave w computes q[ntile w][64 o of pair]
    f32x4 acc[4];
#pragma unroll
    for (int ot = 0; ot < 4; ++ot) acc[ot] = (f32x4){0.f, 0.f, 0.f, 0.f};
    const __bf16* pa = xTf + ((size_t)(b * 1024 + (n0 >> 4) + w) << 12) + (lane << 3);
    const __bf16* pbm = wqf + ((size_t)(hp << 2) << 12) + (lane << 3);
#pragma unroll 2
    for (int cc = 0; cc < 8; ++cc) {
        const int cb = cc << 9;
        bf16x8 af = *(const bf16x8*)&pa[cb];
        bf16x8 bfr[4];
#pragma unroll
        for (int ot = 0; ot < 4; ++ot) bfr[ot] = *(const bf16x8*)&pbm[(ot << 12) + cb];
#pragma unroll
        for (int ot = 0; ot < 4; ++ot)
            acc[ot] = __builtin_amdgcn_mfma_f32_16x16x32_bf16(af, bfr[ot], acc[ot], 0, 0, 0);
    }
#pragma unroll
    for (int ot = 0; ot < 4; ++ot)
#pragma unroll
        for (int r = 0; r < 4; ++r)
            qs[((w << 4) + (quad << 2) + r) * 72 + (ot << 4) + ln] = (__bf16)acc[ot][r];
    __syncthreads();

    // ---------------- score phase: wave w = m range [w*256, w*256+256)
    const f32x4 zf = {0.f, 0.f, 0.f, 0.f};
#pragma unroll
    for (int hl = 0; hl < 2; ++hl) {
        const int h = (hp << 1) + hl;
        bf16x8 qb[4];
#pragma unroll
        for (int nt = 0; nt < 4; ++nt)
            qb[nt] = *(const bf16x8*)&qs[((nt << 4) + ln) * 72 + (hl << 5) + (quad << 3)];
        const __bf16* kb_base = kkbh + ((size_t)(b * 8 + h) << 15) + (ln << 5) + (quad << 3);
        bf16x8 kb[16];
#pragma unroll
        for (int i = 0; i < 16; ++i)
            kb[i] = *(const bf16x8*)&kb_base[((w << 8) + (i << 4)) << 5];
        float rmx[4] = {-INFINITY, -INFINITY, -INFINITY, -INFINITY};
        __builtin_amdgcn_s_setprio(1);
#pragma unroll
        for (int i = 0; i < 16; ++i)
#pragma unroll
            for (int nt = 0; nt < 4; ++nt) {
                f32x4 d = __builtin_amdgcn_mfma_f32_16x16x32_bf16(kb[i], qb[nt], zf, 0, 0, 0);
                float t1 = fmaxf(fmaxf(d[0], d[1]), d[2]);       // -> v_max3
                rmx[nt] = fmaxf(fmaxf(t1, d[3]), rmx[nt]);       // -> v_max3
            }
        __builtin_amdgcn_s_setprio(0);
#pragma unroll
        for (int nt = 0; nt < 4; ++nt) {
            rmx[nt] = fmaxf(rmx[nt], __shfl_xor(rmx[nt], 16, 64));
            rmx[nt] = fmaxf(rmx[nt], __shfl_xor(rmx[nt], 32, 64));
        }
        if (lane < 16) {
#pragma unroll
            for (int nt = 0; nt < 4; ++nt)
                smax[(w << 7) + (hl << 6) + (nt << 4) + lane] = rmx[nt];
        }
    }
    __syncthreads();
    if (t < 64) {
        float s0 = fmaxf(fmaxf(smax[t], smax[128 + t]), fmaxf(smax[256 + t], smax[384 + t]));
        float s1 = fmaxf(fmaxf(smax[64 + t], smax[192 + t]),
                         fmaxf(smax[320 + t], smax[448 + t]));
        atomicAdd(&ssg[(b << 14) + n0 + t], s0 + s1);
    }
    // ---------------- fused epilogue: last of 4 hp blocks writes out slice
    __threadfence();
    __syncthreads();
    if (t == 0)
        sdone = (__hip_atomic_fetch_add(&cnt[(b << 8) + nch], 1,
                                        __ATOMIC_ACQ_REL,
                                        __HIP_MEMORY_SCOPE_AGENT) == 3);
    __syncthreads();
    if (!sdone) return;
    float* sA = (float*)qs;   // qs/smax dead by now; reuse LDS
    float* sB = sA + 256;
    float* sS = sA + 512;
    if (t < 64)
        sS[t] = __hip_atomic_load(&ssg[(b << 14) + n0 + t], __ATOMIC_RELAXED,
                                  __HIP_MEMORY_SCOPE_AGENT);
    sA[t] = A[b * 256 + t];
    sB[t] = B0[t];
    __syncthreads();
#pragma unroll
    for (int i = 0; i < 16; ++i) {
        int e = t + (i << 8);
        int c = e >> 4, n4 = (e & 15) << 2;
        float4 s4 = *(const float4*)&sS[n4];
        float a = sA[c], bb = sB[c];
        float4 o4 = make_float4(fmaf(a, s4.x, bb), fmaf(a, s4.y, bb),
                                fmaf(a, s4.z, bb), fmaf(a, s4.w, bb));
        *(float4*)&out[((size_t)(b * 256 + c) << 14) + n0 + n4] = o4;
    }
}

// ---------------------------------------------------------------------------
extern "C" void kernel_launch(void* const* d_in, const int* in_sizes, int n_in,
                              void* d_out, int out_size, void* d_ws, size_t ws_size,
                              hipStream_t stream) {
    const float* x    = (const float*)d_in[0];
    const float* wq   = (const float*)d_in[1];
    const float* wk   = (const float*)d_in[2];
    const float* wsr  = (const float*)d_in[3];
    const float* sg   = (const float*)d_in[4];
    const float* sb   = (const float*)d_in[5];
    const float* smn  = (const float*)d_in[6];
    const float* svr  = (const float*)d_in[7];
    const float* wproj= (const float*)d_in[8];
    const float* pg   = (const float*)d_in[9];
    const float* pb   = (const float*)d_in[10];
    const float* pm   = (const float*)d_in[11];
    const float* pvr  = (const float*)d_in[12];
    float* out = (float*)d_out;

    char* W = (char*)d_ws;
    float*  w_v   = (float*) (W + 0);          // 512 f
    float*  w_A   = (float*) (W + 4096);       // 512 f
    float*  w_B0  = (float*) (W + 8192);       // 256 f
    float*  w_ssg = (float*) (W + 12288);      // 128 KB (2*16384 f)
    int*    w_cnt = (int*)   (W + 143360);     // 512 i (2 KB, fits pre-wqf gap)
    __bf16* w_wqf = (__bf16*)(W + 147456);     // 128 KB
    __bf16* w_wkb = (__bf16*)(W + 278528);     // 128 KB
    __bf16* w_wsrf= (__bf16*)(W + 409600);     // 2 MB
    __bf16* w_xrb = (__bf16*)(W + 2506752);    // 512 KB
    __bf16* w_kkbh= (__bf16*)(W + 3031040);    // 1 MB
    __bf16* w_Pbf = (__bf16*)(W + 4079616);    // 16.8 MB
    __bf16* w_xTf = (__bf16*)(W + 20856832);   // 16.8 MB

    k_prep<<<1120, 256, 0, stream>>>(wq, wk, wsr, x, w_wqf, w_wkb, w_wsrf, w_Pbf,
                                     w_v, w_ssg, w_cnt);
    k_cx<<<1024, 256, 0, stream>>>(w_Pbf, w_wsrf, sg, sb, smn, svr, w_xrb,
                                   x, w_xTf, w_v);
    k_kmat2<<<130, 256, 0, stream>>>(w_xrb, w_wkb, w_kkbh, w_v, wproj, pg, pb, pm, pvr,
                                     w_A, w_B0);
    k_sc<<<2048, 256, 0, stream>>>(w_xTf, w_wqf, w_kkbh, w_ssg, w_cnt, w_A, w_B0, out);
}

// Round 2
// 401.804 us; speedup vs baseline: 1.2074x; 1.2074x over previous
//
#include <hip/hip_runtime.h>
#include <hip/hip_bf16.h>
#include <math.h>

// Problem constants (B=2, C=256, H=W=128, N=16384, SR=4, HEADS=8, hd=32, M=1024)
#define EPSF 1e-5f
#define SCALE 0.17677669529663687f  // 1/sqrt(32)

typedef __bf16 bf16x8 __attribute__((ext_vector_type(8)));
typedef float f32x4 __attribute__((ext_vector_type(4)));

// Fragment-major layouts (MFMA 16x16x32, A/B frag = [row/col ln<16][k=quad*8+j]):
//   xTf : x^T  [b][n_tile(1024)][cc(8)][lane(64)][j(8)]
//   wqf : w_q  [o_tile(16)][cc(8)][lane][j]
//   Pbf : P    [b][m_tile(64)][cc(128)][lane][j]
//   wsrf: w_sr [o_tile(16)][cc(128)][lane][j]
//   kkbh: k    [b][h(8)][m(1024)][d(32)]
//
// Pipeline (4 launches, NO cross-block atomics/fences anywhere):
//   K1 k_prep : weight conv + zero(v) || im2col              (1088 blocks)
//   K2 k_cx   : conv1f (MFMA-bound) || xT transpose + v (BW) (1024 blocks)
//   K3 k_kmat2: k GEMM + A/B0 prep                           (130 blocks)
//   K4 k_sc   : q + scores (ALL 8 heads per block) + direct
//               output write, fully block-local              (512 blocks)

// ---------------------------------------------------------------------------
// K1: weight conversions + zeroing + im2col.  grid = 576 + 512 = 1088.
__global__ __launch_bounds__(256) void k_prep(const float* __restrict__ wq,
                                              const float* __restrict__ wk,
                                              const float* __restrict__ wsr,
                                              const float* __restrict__ x,
                                              __bf16* __restrict__ wqf,
                                              __bf16* __restrict__ wkb,
                                              __bf16* __restrict__ wsrf,
                                              __bf16* __restrict__ Pbf,
                                              float* __restrict__ v) {
    const int bi = blockIdx.x, t = threadIdx.x;
    if (bi >= 576) {
        // ---- im2col (pure staging, no barriers) ----
        const int bid = bi - 576;
        const int b = bid >> 8, hm = (bid >> 3) & 31, ccg = bid & 7;
        const int wm = t >> 3, c8 = t & 7;
        const int mtile = (hm << 1) + (wm >> 4);
        const int ln = wm & 15;
#pragma unroll
        for (int cci = 0; cci < 4; ++cci) {
            const int c = (ccg << 5) + (cci << 3) + c8;
            const float* src = x + ((size_t)(b * 256 + c) << 14) + (hm << 9) + (wm << 2);
            bf16x8 o0, o1;
#pragma unroll
            for (int p = 0; p < 2; ++p) {
                float4 vv = *(const float4*)&src[p << 7];
                o0[p * 4 + 0] = (__bf16)vv.x; o0[p * 4 + 1] = (__bf16)vv.y;
                o0[p * 4 + 2] = (__bf16)vv.z; o0[p * 4 + 3] = (__bf16)vv.w;
            }
#pragma unroll
            for (int p = 0; p < 2; ++p) {
                float4 vv = *(const float4*)&src[(p + 2) << 7];
                o1[p * 4 + 0] = (__bf16)vv.x; o1[p * 4 + 1] = (__bf16)vv.y;
                o1[p * 4 + 2] = (__bf16)vv.z; o1[p * 4 + 3] = (__bf16)vv.w;
            }
            size_t d0 = (((((size_t)(b * 64 + mtile) << 7) + (c >> 1)) << 6) +
                         (((c & 1) << 1) << 4) + ln) << 3;
            *(bf16x8*)&Pbf[d0] = o0;
            *(bf16x8*)&Pbf[d0 + 128] = o1;
        }
        return;
    }
    if (bi < 32) {
        if (bi == 0) { v[t] = 0.f; v[256 + t] = 0.f; }
        int tt = bi * 256 + t;
        int o = tt >> 5, chunk = tt & 31;
        float4 v0 = *(const float4*)&wq[o * 256 + (chunk << 3)];
        float4 v1 = *(const float4*)&wq[o * 256 + (chunk << 3) + 4];
        bf16x8 p;
        p[0] = (__bf16)v0.x; p[1] = (__bf16)v0.y; p[2] = (__bf16)v0.z; p[3] = (__bf16)v0.w;
        p[4] = (__bf16)v1.x; p[5] = (__bf16)v1.y; p[6] = (__bf16)v1.z; p[7] = (__bf16)v1.w;
        int cc = chunk >> 2, quad = chunk & 3;
        *(bf16x8*)&wqf[(((((o >> 4) << 3) + cc) << 6) + (quad << 4) + (o & 15)) << 3] = p;
    } else if (bi < 64) {
        int e = (bi - 32) * 256 + t;
        float4 v0 = *(const float4*)&wk[e << 3];
        float4 v1 = *(const float4*)&wk[(e << 3) + 4];
        bf16x8 p;
        p[0] = (__bf16)(v0.x * SCALE); p[1] = (__bf16)(v0.y * SCALE);
        p[2] = (__bf16)(v0.z * SCALE); p[3] = (__bf16)(v0.w * SCALE);
        p[4] = (__bf16)(v1.x * SCALE); p[5] = (__bf16)(v1.y * SCALE);
        p[6] = (__bf16)(v1.z * SCALE); p[7] = (__bf16)(v1.w * SCALE);
        *(bf16x8*)&wkb[e << 3] = p;
    } else {
        int tt = (bi - 64) * 256 + t;
        int o = tt >> 9, chunk = tt & 511;
        float4 v0 = *(const float4*)&wsr[o * 4096 + (chunk << 3)];
        float4 v1 = *(const float4*)&wsr[o * 4096 + (chunk << 3) + 4];
        bf16x8 p;
        p[0] = (__bf16)v0.x; p[1] = (__bf16)v0.y; p[2] = (__bf16)v0.z; p[3] = (__bf16)v0.w;
        p[4] = (__bf16)v1.x; p[5] = (__bf16)v1.y; p[6] = (__bf16)v1.z; p[7] = (__bf16)v1.w;
        int cc = chunk >> 2, quad = chunk & 3;
        *(bf16x8*)&wsrf[(((((o >> 4) << 7) + cc) << 6) + (quad << 4) + (o & 15)) << 3] = p;
    }
}

// ---------------------------------------------------------------------------
// K2: blocks 0..511 = conv1f (MFMA GEMM + BN, compute-bound);
//     blocks 512..1023 = xT transpose + v column-sums (BW-bound).
__global__ __launch_bounds__(256) void k_cx(const __bf16* __restrict__ Pbf,
                                            const __bf16* __restrict__ wsrf,
                                            const float* __restrict__ sg,
                                            const float* __restrict__ sb,
                                            const float* __restrict__ smn,
                                            const float* __restrict__ svar,
                                            __bf16* __restrict__ xrb,
                                            const float* __restrict__ x,
                                            __bf16* __restrict__ xTf,
                                            float* __restrict__ v) {
    const int t = threadIdx.x, bid0 = blockIdx.x;
    if (bid0 < 512) {
        // ---- conv1f ----
        const int b = bid0 & 1, mt = (bid0 >> 1) & 63, og = bid0 >> 7;
        const int w = t >> 6, lane = t & 63, ln = lane & 15, quad = lane >> 4;
        f32x4 acc = (f32x4){0.f, 0.f, 0.f, 0.f};
        const __bf16* pa = Pbf + ((size_t)(b * 64 + mt) << 16) + (lane << 3);
        const __bf16* pbm = wsrf + ((size_t)(og * 4 + w) << 16) + (lane << 3);
#pragma unroll 8
        for (int cc = 0; cc < 128; ++cc) {
            bf16x8 af = *(const bf16x8*)&pa[cc << 9];
            bf16x8 bf = *(const bf16x8*)&pbm[cc << 9];
            acc = __builtin_amdgcn_mfma_f32_16x16x32_bf16(af, bf, acc, 0, 0, 0);
        }
        const int o = (og << 6) + (w << 4) + ln;
        float inv = sg[o] / sqrtf(svar[o] + EPSF);
        float mn = smn[o], bt = sb[o];
#pragma unroll
        for (int r = 0; r < 4; ++r) {
            int m = (mt << 4) + (quad << 2) + r;
            xrb[(((size_t)b << 10) + m) * 256 + o] = (__bf16)((acc[r] - mn) * inv + bt);
        }
    } else {
        // ---- xT + v ----
        __shared__ float ts[32 * 68];
        __shared__ float sv[256];
        const int bid = bid0 - 512;
        const int b = bid >> 8, n0 = (bid & 255) << 6;
        const int nl = t >> 2;
        const int ch = (t & 3) << 3;
        const int n = n0 + nl;
        const int ntile = n >> 4, ln = n & 15, quad = ch >> 3;
        const int cl = t >> 3;
        const int n8 = (t & 7) << 3;
        sv[t] = 0.f;
        for (int s8 = 0; s8 < 8; ++s8) {
            const int c0 = s8 << 5;
            __syncthreads();
            {
                const float* src = &x[((size_t)(b * 256 + c0 + cl) << 14) + n0 + n8];
                float4 a0 = *(const float4*)&src[0];
                float4 a1 = *(const float4*)&src[4];
                *(float4*)&ts[cl * 68 + n8] = a0;
                *(float4*)&ts[cl * 68 + n8 + 4] = a1;
                atomicAdd(&sv[c0 + cl],
                          a0.x + a0.y + a0.z + a0.w + a1.x + a1.y + a1.z + a1.w);
            }
            __syncthreads();
            bf16x8 p;
#pragma unroll
            for (int j = 0; j < 8; ++j) p[j] = (__bf16)ts[(ch + j) * 68 + nl];
            *(bf16x8*)&xTf[(((((size_t)(b * 1024 + ntile) << 3) + s8) << 6) +
                            (quad << 4) + ln) << 3] = p;
        }
        __syncthreads();
        atomicAdd(&v[b * 256 + t], sv[t]);
    }
}

// ---------------------------------------------------------------------------
// K3: MFMA GEMM kkbh = xrb x wkb (blocks 0..127) + k_ab work (128..129).
__global__ __launch_bounds__(256) void k_kmat2(const __bf16* __restrict__ xrb,
                                               const __bf16* __restrict__ wkb,
                                               __bf16* __restrict__ kkbh,
                                               const float* __restrict__ v,
                                               const float* __restrict__ wproj,
                                               const float* __restrict__ pg,
                                               const float* __restrict__ pb,
                                               const float* __restrict__ pm,
                                               const float* __restrict__ pvar,
                                               float* __restrict__ A,
                                               float* __restrict__ B0) {
    const int t = threadIdx.x, bid = blockIdx.x;
    if (bid >= 128) {
        // ---- k_ab ----
        __shared__ float vl[256];
        int b = bid - 128;
        vl[t] = v[b * 256 + t] * (1.0f / 16384.0f);
        __syncthreads();
        const float* wr = wproj + t * 256;
        float s = 0.f;
#pragma unroll 8
        for (int c = 0; c < 256; c += 4) {
            float4 w4 = *(const float4*)&wr[c];
            s += w4.x * vl[c] + w4.y * vl[c + 1] + w4.z * vl[c + 2] + w4.w * vl[c + 3];
        }
        float inv = pg[t] / sqrtf(pvar[t] + EPSF);
        A[b * 256 + t] = s * inv;
        if (b == 0) B0[t] = pb[t] - pm[t] * inv;
        return;
    }
    const int b = bid >> 6, mt = bid & 63;
    const int w = t >> 6, lane = t & 63, ln = lane & 15, quad = lane >> 4;
    f32x4 acc[4];
#pragma unroll
    for (int ot = 0; ot < 4; ++ot) acc[ot] = (f32x4){0.f, 0.f, 0.f, 0.f};
    const __bf16* pa = xrb + ((((size_t)b << 10) + (mt << 4) + ln) << 8) + (quad << 3);
    const __bf16* pbm = wkb + (((w << 6) + ln) << 8) + (quad << 3);
#pragma unroll
    for (int cc = 0; cc < 8; ++cc) {
        const int cb = cc << 5;
        bf16x8 af = *(const bf16x8*)&pa[cb];
        bf16x8 bfr[4];
#pragma unroll
        for (int ot = 0; ot < 4; ++ot) bfr[ot] = *(const bf16x8*)&pbm[(ot << 12) + cb];
#pragma unroll
        for (int ot = 0; ot < 4; ++ot)
            acc[ot] = __builtin_amdgcn_mfma_f32_16x16x32_bf16(af, bfr[ot], acc[ot], 0, 0, 0);
    }
#pragma unroll
    for (int ot = 0; ot < 4; ++ot)
#pragma unroll
        for (int r = 0; r < 4; ++r) {
            int m = (mt << 4) + (quad << 2) + r;
            int h = (w << 1) + (ot >> 1);
            int d = ((ot & 1) << 4) + ln;
            kkbh[(((size_t)(b * 8 + h)) << 15) + (m << 5) + d] = (__bf16)acc[ot][r];
        }
}

// ---------------------------------------------------------------------------
// K4: q + scores for ALL 8 heads + direct output write.
// grid = b(2) x nchunk(256) = 512.  Everything block-local: no atomics,
// no fences, no ssg buffer.  Output write overlaps other blocks' MFMA.
#define QP 264  // qs row pitch in bf16 (64 n rows x 256 o cols, pad 8)
__global__ __launch_bounds__(256) void k_sc(const __bf16* __restrict__ xTf,
                                            const __bf16* __restrict__ wqf,
                                            const __bf16* __restrict__ kkbh,
                                            const float* __restrict__ A,
                                            const float* __restrict__ B0,
                                            float* __restrict__ out) {
    __shared__ __align__(16) __bf16 qs[64 * QP];   // [n(64)][o(256)+pad]
    __shared__ float smax[4 * 8 * 64];             // [w][h][n64]
    const int t = threadIdx.x;
    const int w = t >> 6;
    const int lane = t & 63;
    const int ln = lane & 15;
    const int quad = lane >> 4;
    const int bx = blockIdx.x;
    const int nch = bx & 255;
    const int n0 = nch << 6;
    const int b = bx >> 8;

    // ---------------- q phase: wave w = n-tile w; all 16 o-tiles (256 o)
    const __bf16* pa = xTf + ((size_t)(b * 1024 + (n0 >> 4) + w) << 12) + (lane << 3);
    bf16x8 af[8];
#pragma unroll
    for (int cc = 0; cc < 8; ++cc) af[cc] = *(const bf16x8*)&pa[cc << 9];
#pragma unroll
    for (int og = 0; og < 4; ++og) {
        const __bf16* pbm = wqf + ((size_t)(og << 2) << 12) + (lane << 3);
        f32x4 acc[4];
#pragma unroll
        for (int ot = 0; ot < 4; ++ot) acc[ot] = (f32x4){0.f, 0.f, 0.f, 0.f};
#pragma unroll 2
        for (int cc = 0; cc < 8; ++cc) {
            const int cb = cc << 9;
            bf16x8 bfr[4];
#pragma unroll
            for (int ot = 0; ot < 4; ++ot) bfr[ot] = *(const bf16x8*)&pbm[(ot << 12) + cb];
#pragma unroll
            for (int ot = 0; ot < 4; ++ot)
                acc[ot] = __builtin_amdgcn_mfma_f32_16x16x32_bf16(af[cc], bfr[ot],
                                                                  acc[ot], 0, 0, 0);
        }
#pragma unroll
        for (int ot = 0; ot < 4; ++ot)
#pragma unroll
            for (int r = 0; r < 4; ++r)
                qs[((w << 4) + (quad << 2) + r) * QP + (og << 6) + (ot << 4) + ln] =
                    (__bf16)acc[ot][r];
    }
    __syncthreads();

    // ---------------- score phase: wave w = m range [w*256, w*256+256)
    const f32x4 zf = {0.f, 0.f, 0.f, 0.f};
#pragma unroll
    for (int h = 0; h < 8; ++h) {
        bf16x8 qb[4];
#pragma unroll
        for (int nt = 0; nt < 4; ++nt)
            qb[nt] = *(const bf16x8*)&qs[((nt << 4) + ln) * QP + (h << 5) + (quad << 3)];
        const __bf16* kb_base = kkbh + ((size_t)(b * 8 + h) << 15) + (ln << 5) + (quad << 3);
        bf16x8 kb[16];
#pragma unroll
        for (int i = 0; i < 16; ++i)
            kb[i] = *(const bf16x8*)&kb_base[((w << 8) + (i << 4)) << 5];
        float rmx[4] = {-INFINITY, -INFINITY, -INFINITY, -INFINITY};
        __builtin_amdgcn_s_setprio(1);
#pragma unroll
        for (int i = 0; i < 16; ++i)
#pragma unroll
            for (int nt = 0; nt < 4; ++nt) {
                f32x4 d = __builtin_amdgcn_mfma_f32_16x16x32_bf16(kb[i], qb[nt], zf, 0, 0, 0);
                float t1 = fmaxf(fmaxf(d[0], d[1]), d[2]);       // -> v_max3
                rmx[nt] = fmaxf(fmaxf(t1, d[3]), rmx[nt]);       // -> v_max3
            }
        __builtin_amdgcn_s_setprio(0);
#pragma unroll
        for (int nt = 0; nt < 4; ++nt) {
            rmx[nt] = fmaxf(rmx[nt], __shfl_xor(rmx[nt], 16, 64));
            rmx[nt] = fmaxf(rmx[nt], __shfl_xor(rmx[nt], 32, 64));
        }
        if (lane < 16) {
#pragma unroll
            for (int nt = 0; nt < 4; ++nt)
                smax[(((w << 3) + h) << 6) + (nt << 4) + lane] = rmx[nt];
        }
    }
    __syncthreads();

    // ---------------- block-local reduce (sum over h of max over w) + epilogue
    float* sS = (float*)qs;        // qs dead now; reuse as f32 scratch
    float* sA = sS + 64;
    float* sB = sS + 320;
    if (t < 64) {
        float s = 0.f;
#pragma unroll
        for (int h = 0; h < 8; ++h) {
            const int o0 = (h << 6) + t;
            s += fmaxf(fmaxf(smax[o0], smax[o0 + 512]),
                       fmaxf(smax[o0 + 1024], smax[o0 + 1536]));
        }
        sS[t] = s;
    }
    sA[t] = A[b * 256 + t];
    sB[t] = B0[t];
    __syncthreads();
#pragma unroll
    for (int i = 0; i < 16; ++i) {
        int e = t + (i << 8);
        int c = e >> 4, n4 = (e & 15) << 2;
        float4 s4 = *(const float4*)&sS[n4];
        float a = sA[c], bb = sB[c];
        float4 o4 = make_float4(fmaf(a, s4.x, bb), fmaf(a, s4.y, bb),
                                fmaf(a, s4.z, bb), fmaf(a, s4.w, bb));
        *(float4*)&out[((size_t)(b * 256 + c) << 14) + n0 + n4] = o4;
    }
}

// ---------------------------------------------------------------------------
extern "C" void kernel_launch(void* const* d_in, const int* in_sizes, int n_in,
                              void* d_out, int out_size, void* d_ws, size_t ws_size,
                              hipStream_t stream) {
    const float* x    = (const float*)d_in[0];
    const float* wq   = (const float*)d_in[1];
    const float* wk   = (const float*)d_in[2];
    const float* wsr  = (const float*)d_in[3];
    const float* sg   = (const float*)d_in[4];
    const float* sb   = (const float*)d_in[5];
    const float* smn  = (const float*)d_in[6];
    const float* svr  = (const float*)d_in[7];
    const float* wproj= (const float*)d_in[8];
    const float* pg   = (const float*)d_in[9];
    const float* pb   = (const float*)d_in[10];
    const float* pm   = (const float*)d_in[11];
    const float* pvr  = (const float*)d_in[12];
    float* out = (float*)d_out;

    char* W = (char*)d_ws;
    float*  w_v   = (float*) (W + 0);          // 512 f
    float*  w_A   = (float*) (W + 4096);       // 512 f
    float*  w_B0  = (float*) (W + 8192);       // 256 f
    __bf16* w_wqf = (__bf16*)(W + 147456);     // 128 KB
    __bf16* w_wkb = (__bf16*)(W + 278528);     // 128 KB
    __bf16* w_wsrf= (__bf16*)(W + 409600);     // 2 MB
    __bf16* w_xrb = (__bf16*)(W + 2506752);    // 512 KB
    __bf16* w_kkbh= (__bf16*)(W + 3031040);    // 1 MB
    __bf16* w_Pbf = (__bf16*)(W + 4079616);    // 16.8 MB
    __bf16* w_xTf = (__bf16*)(W + 20856832);   // 16.8 MB

    k_prep<<<1088, 256, 0, stream>>>(wq, wk, wsr, x, w_wqf, w_wkb, w_wsrf, w_Pbf, w_v);
    k_cx<<<1024, 256, 0, stream>>>(w_Pbf, w_wsrf, sg, sb, smn, svr, w_xrb,
                                   x, w_xTf, w_v);
    k_kmat2<<<130, 256, 0, stream>>>(w_xrb, w_wkb, w_kkbh, w_v, wproj, pg, pb, pm, pvr,
                                     w_A, w_B0);
    k_sc<<<512, 256, 0, stream>>>(w_xTf, w_wqf, w_kkbh, w_A, w_B0, out);
}

// Round 3
// 272.038 us; speedup vs baseline: 1.7834x; 1.4770x over previous
//
#include <hip/hip_runtime.h>
#include <hip/hip_bf16.h>
#include <math.h>

// Problem constants (B=2, C=256, H=W=128, N=16384, SR=4, HEADS=8, hd=32, M=1024)
#define EPSF 1e-5f
#define SCALE 0.17677669529663687f  // 1/sqrt(32)

typedef __bf16 bf16x8 __attribute__((ext_vector_type(8)));
typedef float f32x4 __attribute__((ext_vector_type(4)));

// Fragment-major layouts (MFMA 16x16x32, A/B frag = [row/col ln<16][k=quad*8+j]):
//   xTf : x^T  [b][n_tile(1024)][cc(8)][lane(64)][j(8)]
//   wqf : w_q  [o_tile(16)][cc(8)][lane][j]
//   Pbf : P    [b][m_tile(64)][cc(128)][lane][j]
//   wsrf: w_sr [o_tile(16)][cc(128)][lane][j]
//   kkbh: k    [b][h(8)][m(1024)][d(32)]
//
// Pipeline (4 launches, NO cross-block atomics/fences anywhere):
//   K1 k_prep : weight conv + zero(v) || im2col              (1088 blocks)
//   K2 k_cx   : conv1f || xT, parity-interleaved             (1024 blocks)
//   K3 k_kmat2: k GEMM + A/B0 prep                           (130 blocks)
//   K4 k_sc   : 512 threads, wave=head; q + scores + direct
//               output write, fully block-local              (512 blocks)

// ---------------------------------------------------------------------------
// K1: weight conversions + zeroing + im2col.  grid = 576 + 512 = 1088.
__global__ __launch_bounds__(256) void k_prep(const float* __restrict__ wq,
                                              const float* __restrict__ wk,
                                              const float* __restrict__ wsr,
                                              const float* __restrict__ x,
                                              __bf16* __restrict__ wqf,
                                              __bf16* __restrict__ wkb,
                                              __bf16* __restrict__ wsrf,
                                              __bf16* __restrict__ Pbf,
                                              float* __restrict__ v) {
    const int bi = blockIdx.x, t = threadIdx.x;
    if (bi >= 576) {
        // ---- im2col (pure staging, no barriers) ----
        const int bid = bi - 576;
        const int b = bid >> 8, hm = (bid >> 3) & 31, ccg = bid & 7;
        const int wm = t >> 3, c8 = t & 7;
        const int mtile = (hm << 1) + (wm >> 4);
        const int ln = wm & 15;
#pragma unroll
        for (int cci = 0; cci < 4; ++cci) {
            const int c = (ccg << 5) + (cci << 3) + c8;
            const float* src = x + ((size_t)(b * 256 + c) << 14) + (hm << 9) + (wm << 2);
            bf16x8 o0, o1;
#pragma unroll
            for (int p = 0; p < 2; ++p) {
                float4 vv = *(const float4*)&src[p << 7];
                o0[p * 4 + 0] = (__bf16)vv.x; o0[p * 4 + 1] = (__bf16)vv.y;
                o0[p * 4 + 2] = (__bf16)vv.z; o0[p * 4 + 3] = (__bf16)vv.w;
            }
#pragma unroll
            for (int p = 0; p < 2; ++p) {
                float4 vv = *(const float4*)&src[(p + 2) << 7];
                o1[p * 4 + 0] = (__bf16)vv.x; o1[p * 4 + 1] = (__bf16)vv.y;
                o1[p * 4 + 2] = (__bf16)vv.z; o1[p * 4 + 3] = (__bf16)vv.w;
            }
            size_t d0 = (((((size_t)(b * 64 + mtile) << 7) + (c >> 1)) << 6) +
                         (((c & 1) << 1) << 4) + ln) << 3;
            *(bf16x8*)&Pbf[d0] = o0;
            *(bf16x8*)&Pbf[d0 + 128] = o1;
        }
        return;
    }
    if (bi < 32) {
        if (bi == 0) { v[t] = 0.f; v[256 + t] = 0.f; }
        int tt = bi * 256 + t;
        int o = tt >> 5, chunk = tt & 31;
        float4 v0 = *(const float4*)&wq[o * 256 + (chunk << 3)];
        float4 v1 = *(const float4*)&wq[o * 256 + (chunk << 3) + 4];
        bf16x8 p;
        p[0] = (__bf16)v0.x; p[1] = (__bf16)v0.y; p[2] = (__bf16)v0.z; p[3] = (__bf16)v0.w;
        p[4] = (__bf16)v1.x; p[5] = (__bf16)v1.y; p[6] = (__bf16)v1.z; p[7] = (__bf16)v1.w;
        int cc = chunk >> 2, quad = chunk & 3;
        *(bf16x8*)&wqf[(((((o >> 4) << 3) + cc) << 6) + (quad << 4) + (o & 15)) << 3] = p;
    } else if (bi < 64) {
        int e = (bi - 32) * 256 + t;
        float4 v0 = *(const float4*)&wk[e << 3];
        float4 v1 = *(const float4*)&wk[(e << 3) + 4];
        bf16x8 p;
        p[0] = (__bf16)(v0.x * SCALE); p[1] = (__bf16)(v0.y * SCALE);
        p[2] = (__bf16)(v0.z * SCALE); p[3] = (__bf16)(v0.w * SCALE);
        p[4] = (__bf16)(v1.x * SCALE); p[5] = (__bf16)(v1.y * SCALE);
        p[6] = (__bf16)(v1.z * SCALE); p[7] = (__bf16)(v1.w * SCALE);
        *(bf16x8*)&wkb[e << 3] = p;
    } else {
        int tt = (bi - 64) * 256 + t;
        int o = tt >> 9, chunk = tt & 511;
        float4 v0 = *(const float4*)&wsr[o * 4096 + (chunk << 3)];
        float4 v1 = *(const float4*)&wsr[o * 4096 + (chunk << 3) + 4];
        bf16x8 p;
        p[0] = (__bf16)v0.x; p[1] = (__bf16)v0.y; p[2] = (__bf16)v0.z; p[3] = (__bf16)v0.w;
        p[4] = (__bf16)v1.x; p[5] = (__bf16)v1.y; p[6] = (__bf16)v1.z; p[7] = (__bf16)v1.w;
        int cc = chunk >> 2, quad = chunk & 3;
        *(bf16x8*)&wsrf[(((((o >> 4) << 7) + cc) << 6) + (quad << 4) + (o & 15)) << 3] = p;
    }
}

// ---------------------------------------------------------------------------
// K2: parity-interleaved: even blocks = conv1f (MFMA-bound), odd = xT+v (BW).
// Each CU gets a mix of both pipes.
__global__ __launch_bounds__(256) void k_cx(const __bf16* __restrict__ Pbf,
                                            const __bf16* __restrict__ wsrf,
                                            const float* __restrict__ sg,
                                            const float* __restrict__ sb,
                                            const float* __restrict__ smn,
                                            const float* __restrict__ svar,
                                            __bf16* __restrict__ xrb,
                                            const float* __restrict__ x,
                                            __bf16* __restrict__ xTf,
                                            float* __restrict__ v) {
    const int t = threadIdx.x, bid0 = blockIdx.x;
    if ((bid0 & 1) == 0) {
        // ---- conv1f ----
        const int cid = bid0 >> 1;
        const int b = cid & 1, mt = (cid >> 1) & 63, og = cid >> 7;
        const int w = t >> 6, lane = t & 63, ln = lane & 15, quad = lane >> 4;
        f32x4 acc = (f32x4){0.f, 0.f, 0.f, 0.f};
        const __bf16* pa = Pbf + ((size_t)(b * 64 + mt) << 16) + (lane << 3);
        const __bf16* pbm = wsrf + ((size_t)(og * 4 + w) << 16) + (lane << 3);
#pragma unroll 8
        for (int cc = 0; cc < 128; ++cc) {
            bf16x8 af = *(const bf16x8*)&pa[cc << 9];
            bf16x8 bf = *(const bf16x8*)&pbm[cc << 9];
            acc = __builtin_amdgcn_mfma_f32_16x16x32_bf16(af, bf, acc, 0, 0, 0);
        }
        const int o = (og << 6) + (w << 4) + ln;
        float inv = sg[o] / sqrtf(svar[o] + EPSF);
        float mn = smn[o], bt = sb[o];
#pragma unroll
        for (int r = 0; r < 4; ++r) {
            int m = (mt << 4) + (quad << 2) + r;
            xrb[(((size_t)b << 10) + m) * 256 + o] = (__bf16)((acc[r] - mn) * inv + bt);
        }
    } else {
        // ---- xT + v ----
        __shared__ float ts[32 * 68];
        __shared__ float sv[256];
        const int bid = bid0 >> 1;
        const int b = bid >> 8, n0 = (bid & 255) << 6;
        const int nl = t >> 2;
        const int ch = (t & 3) << 3;
        const int n = n0 + nl;
        const int ntile = n >> 4, ln = n & 15, quad = ch >> 3;
        const int cl = t >> 3;
        const int n8 = (t & 7) << 3;
        sv[t] = 0.f;
        for (int s8 = 0; s8 < 8; ++s8) {
            const int c0 = s8 << 5;
            __syncthreads();
            {
                const float* src = &x[((size_t)(b * 256 + c0 + cl) << 14) + n0 + n8];
                float4 a0 = *(const float4*)&src[0];
                float4 a1 = *(const float4*)&src[4];
                *(float4*)&ts[cl * 68 + n8] = a0;
                *(float4*)&ts[cl * 68 + n8 + 4] = a1;
                atomicAdd(&sv[c0 + cl],
                          a0.x + a0.y + a0.z + a0.w + a1.x + a1.y + a1.z + a1.w);
            }
            __syncthreads();
            bf16x8 p;
#pragma unroll
            for (int j = 0; j < 8; ++j) p[j] = (__bf16)ts[(ch + j) * 68 + nl];
            *(bf16x8*)&xTf[(((((size_t)(b * 1024 + ntile) << 3) + s8) << 6) +
                            (quad << 4) + ln) << 3] = p;
        }
        __syncthreads();
        atomicAdd(&v[b * 256 + t], sv[t]);
    }
}

// ---------------------------------------------------------------------------
// K3: MFMA GEMM kkbh = xrb x wkb (blocks 0..127) + k_ab work (128..129).
__global__ __launch_bounds__(256) void k_kmat2(const __bf16* __restrict__ xrb,
                                               const __bf16* __restrict__ wkb,
                                               __bf16* __restrict__ kkbh,
                                               const float* __restrict__ v,
                                               const float* __restrict__ wproj,
                                               const float* __restrict__ pg,
                                               const float* __restrict__ pb,
                                               const float* __restrict__ pm,
                                               const float* __restrict__ pvar,
                                               float* __restrict__ A,
                                               float* __restrict__ B0) {
    const int t = threadIdx.x, bid = blockIdx.x;
    if (bid >= 128) {
        // ---- k_ab ----
        __shared__ float vl[256];
        int b = bid - 128;
        vl[t] = v[b * 256 + t] * (1.0f / 16384.0f);
        __syncthreads();
        const float* wr = wproj + t * 256;
        float s = 0.f;
#pragma unroll 8
        for (int c = 0; c < 256; c += 4) {
            float4 w4 = *(const float4*)&wr[c];
            s += w4.x * vl[c] + w4.y * vl[c + 1] + w4.z * vl[c + 2] + w4.w * vl[c + 3];
        }
        float inv = pg[t] / sqrtf(pvar[t] + EPSF);
        A[b * 256 + t] = s * inv;
        if (b == 0) B0[t] = pb[t] - pm[t] * inv;
        return;
    }
    const int b = bid >> 6, mt = bid & 63;
    const int w = t >> 6, lane = t & 63, ln = lane & 15, quad = lane >> 4;
    f32x4 acc[4];
#pragma unroll
    for (int ot = 0; ot < 4; ++ot) acc[ot] = (f32x4){0.f, 0.f, 0.f, 0.f};
    const __bf16* pa = xrb + ((((size_t)b << 10) + (mt << 4) + ln) << 8) + (quad << 3);
    const __bf16* pbm = wkb + (((w << 6) + ln) << 8) + (quad << 3);
#pragma unroll
    for (int cc = 0; cc < 8; ++cc) {
        const int cb = cc << 5;
        bf16x8 af = *(const bf16x8*)&pa[cb];
        bf16x8 bfr[4];
#pragma unroll
        for (int ot = 0; ot < 4; ++ot) bfr[ot] = *(const bf16x8*)&pbm[(ot << 12) + cb];
#pragma unroll
        for (int ot = 0; ot < 4; ++ot)
            acc[ot] = __builtin_amdgcn_mfma_f32_16x16x32_bf16(af, bfr[ot], acc[ot], 0, 0, 0);
    }
#pragma unroll
    for (int ot = 0; ot < 4; ++ot)
#pragma unroll
        for (int r = 0; r < 4; ++r) {
            int m = (mt << 4) + (quad << 2) + r;
            int h = (w << 1) + (ot >> 1);
            int d = ((ot & 1) << 4) + ln;
            kkbh[(((size_t)(b * 8 + h)) << 15) + (m << 5) + d] = (__bf16)acc[ot][r];
        }
}

// ---------------------------------------------------------------------------
// K4: 512 threads (8 waves).  q phase: wave w = (ntile w>>1, o-half w&1).
// Score phase: wave w = head w over ALL m=1024 (head-max is wave-local).
// Block-local h-sum + direct output write.  grid = b(2) x nchunk(256) = 512.
#define QP 264  // qs row pitch in bf16 (64 n rows x 256 o cols, pad 8)
__global__ __launch_bounds__(512, 4) void k_sc(const __bf16* __restrict__ xTf,
                                               const __bf16* __restrict__ wqf,
                                               const __bf16* __restrict__ kkbh,
                                               const float* __restrict__ A,
                                               const float* __restrict__ B0,
                                               float* __restrict__ out) {
    __shared__ __align__(16) __bf16 qs[64 * QP];   // [n(64)][o(256)+pad] = 33.8 KB
    __shared__ float smax[512];                    // [wave/head(8)][n64]
    const int t = threadIdx.x;
    const int w = t >> 6;
    const int lane = t & 63;
    const int ln = lane & 15;
    const int quad = lane >> 4;
    const int bx = blockIdx.x;
    const int nch = bx & 255;
    const int n0 = nch << 6;
    const int b = bx >> 8;

    // ---------------- q phase: wave w: n-tile (w>>1), o-half (w&1), 64 MFMA
    {
        const __bf16* pa = xTf +
            ((size_t)(b * 1024 + (n0 >> 4) + (w >> 1)) << 12) + (lane << 3);
        bf16x8 af[8];
#pragma unroll
        for (int cc = 0; cc < 8; ++cc) af[cc] = *(const bf16x8*)&pa[cc << 9];
        const int oh = w & 1;
#pragma unroll
        for (int ot = 0; ot < 8; ++ot) {
            const __bf16* pbm = wqf + ((size_t)((oh << 3) + ot) << 12) + (lane << 3);
            f32x4 acc = (f32x4){0.f, 0.f, 0.f, 0.f};
#pragma unroll
            for (int cc = 0; cc < 8; ++cc) {
                bf16x8 bf = *(const bf16x8*)&pbm[cc << 9];
                acc = __builtin_amdgcn_mfma_f32_16x16x32_bf16(af[cc], bf, acc, 0, 0, 0);
            }
#pragma unroll
            for (int r = 0; r < 4; ++r)
                qs[(((w >> 1) << 4) + (quad << 2) + r) * QP +
                   (oh << 7) + (ot << 4) + ln] = (__bf16)acc[r];
        }
    }
    __syncthreads();

    // ---------------- score phase: wave w = head w, m = 0..1023
    {
        const int h = w;
        bf16x8 qb[4];
#pragma unroll
        for (int nt = 0; nt < 4; ++nt)
            qb[nt] = *(const bf16x8*)&qs[((nt << 4) + ln) * QP + (h << 5) + (quad << 3)];
        const __bf16* kb_base = kkbh + ((size_t)(b * 8 + h) << 15) + (ln << 5) + (quad << 3);
        const f32x4 zf = {0.f, 0.f, 0.f, 0.f};
        float rmx[4] = {-INFINITY, -INFINITY, -INFINITY, -INFINITY};
        bf16x8 ka[8], kc[8];
        // chunk c covers i = c*8+j (16 m each); addr = kb_base[i<<9]
#pragma unroll
        for (int j = 0; j < 8; ++j) ka[j] = *(const bf16x8*)&kb_base[j << 9];
#pragma unroll
        for (int c0 = 0; c0 < 8; c0 += 2) {
#pragma unroll
            for (int j = 0; j < 8; ++j)
                kc[j] = *(const bf16x8*)&kb_base[(((c0 + 1) << 3) + j) << 9];
            __builtin_amdgcn_s_setprio(1);
#pragma unroll
            for (int j = 0; j < 8; ++j)
#pragma unroll
                for (int nt = 0; nt < 4; ++nt) {
                    f32x4 d = __builtin_amdgcn_mfma_f32_16x16x32_bf16(ka[j], qb[nt],
                                                                      zf, 0, 0, 0);
                    float t1 = fmaxf(fmaxf(d[0], d[1]), d[2]);   // -> v_max3
                    rmx[nt] = fmaxf(fmaxf(t1, d[3]), rmx[nt]);   // -> v_max3
                }
            __builtin_amdgcn_s_setprio(0);
            if (c0 + 2 < 8) {
#pragma unroll
                for (int j = 0; j < 8; ++j)
                    ka[j] = *(const bf16x8*)&kb_base[(((c0 + 2) << 3) + j) << 9];
            }
            __builtin_amdgcn_s_setprio(1);
#pragma unroll
            for (int j = 0; j < 8; ++j)
#pragma unroll
                for (int nt = 0; nt < 4; ++nt) {
                    f32x4 d = __builtin_amdgcn_mfma_f32_16x16x32_bf16(kc[j], qb[nt],
                                                                      zf, 0, 0, 0);
                    float t1 = fmaxf(fmaxf(d[0], d[1]), d[2]);
                    rmx[nt] = fmaxf(fmaxf(t1, d[3]), rmx[nt]);
                }
            __builtin_amdgcn_s_setprio(0);
        }
#pragma unroll
        for (int nt = 0; nt < 4; ++nt) {
            rmx[nt] = fmaxf(rmx[nt], __shfl_xor(rmx[nt], 16, 64));
            rmx[nt] = fmaxf(rmx[nt], __shfl_xor(rmx[nt], 32, 64));
        }
        if (lane < 16) {
#pragma unroll
            for (int nt = 0; nt < 4; ++nt)
                smax[(w << 6) + (nt << 4) + lane] = rmx[nt];
        }
    }
    __syncthreads();

    // ---------------- block-local h-sum + epilogue (reuse qs as f32 scratch)
    float* sS = (float*)qs;
    float* sA = sS + 64;
    float* sB = sS + 320;
    if (t < 256) sA[t] = A[b * 256 + t];
    else sB[t - 256] = B0[t - 256];
    if (t < 64) {
        float s = 0.f;
#pragma unroll
        for (int h = 0; h < 8; ++h) s += smax[(h << 6) + t];
        sS[t] = s;
    }
    __syncthreads();
#pragma unroll
    for (int i = 0; i < 8; ++i) {
        int e = t + (i << 9);
        int c = e >> 4, n4 = (e & 15) << 2;
        float4 s4 = *(const float4*)&sS[n4];
        float a = sA[c], bb = sB[c];
        float4 o4 = make_float4(fmaf(a, s4.x, bb), fmaf(a, s4.y, bb),
                                fmaf(a, s4.z, bb), fmaf(a, s4.w, bb));
        *(float4*)&out[((size_t)(b * 256 + c) << 14) + n0 + n4] = o4;
    }
}

// ---------------------------------------------------------------------------
extern "C" void kernel_launch(void* const* d_in, const int* in_sizes, int n_in,
                              void* d_out, int out_size, void* d_ws, size_t ws_size,
                              hipStream_t stream) {
    const float* x    = (const float*)d_in[0];
    const float* wq   = (const float*)d_in[1];
    const float* wk   = (const float*)d_in[2];
    const float* wsr  = (const float*)d_in[3];
    const float* sg   = (const float*)d_in[4];
    const float* sb   = (const float*)d_in[5];
    const float* smn  = (const float*)d_in[6];
    const float* svr  = (const float*)d_in[7];
    const float* wproj= (const float*)d_in[8];
    const float* pg   = (const float*)d_in[9];
    const float* pb   = (const float*)d_in[10];
    const float* pm   = (const float*)d_in[11];
    const float* pvr  = (const float*)d_in[12];
    float* out = (float*)d_out;

    char* W = (char*)d_ws;
    float*  w_v   = (float*) (W + 0);          // 512 f
    float*  w_A   = (float*) (W + 4096);       // 512 f
    float*  w_B0  = (float*) (W + 8192);       // 256 f
    __bf16* w_wqf = (__bf16*)(W + 147456);     // 128 KB
    __bf16* w_wkb = (__bf16*)(W + 278528);     // 128 KB
    __bf16* w_wsrf= (__bf16*)(W + 409600);     // 2 MB
    __bf16* w_xrb = (__bf16*)(W + 2506752);    // 512 KB
    __bf16* w_kkbh= (__bf16*)(W + 3031040);    // 1 MB
    __bf16* w_Pbf = (__bf16*)(W + 4079616);    // 16.8 MB
    __bf16* w_xTf = (__bf16*)(W + 20856832);   // 16.8 MB

    k_prep<<<1088, 256, 0, stream>>>(wq, wk, wsr, x, w_wqf, w_wkb, w_wsrf, w_Pbf, w_v);
    k_cx<<<1024, 256, 0, stream>>>(w_Pbf, w_wsrf, sg, sb, smn, svr, w_xrb,
                                   x, w_xTf, w_v);
    k_kmat2<<<130, 256, 0, stream>>>(w_xrb, w_wkb, w_kkbh, w_v, wproj, pg, pb, pm, pvr,
                                     w_A, w_B0);
    k_sc<<<512, 512, 0, stream>>>(w_xTf, w_wqf, w_kkbh, w_A, w_B0, out);
}

// Round 4
// 200.834 us; speedup vs baseline: 2.4156x; 1.3545x over previous
//
#include <hip/hip_runtime.h>
#include <hip/hip_bf16.h>
#include <math.h>

// Problem constants (B=2, C=256, H=W=128, N=16384, SR=4, HEADS=8, hd=32, M=1024)
#define EPSF 1e-5f
#define SCALE 0.17677669529663687f  // 1/sqrt(32)

typedef __bf16 bf16x8 __attribute__((ext_vector_type(8)));
typedef float f32x4 __attribute__((ext_vector_type(4)));

// Fragment-major layouts (MFMA 16x16x32, A/B frag = [row/col ln<16][k=quad*8+j]):
//   xTf : x^T  [b][n_tile(1024)][cc(8)][lane(64)][j(8)]
//   wqf : w_q  [o_tile(16)][cc(8)][lane][j]
//   Pbf : P    [b][m_tile(64)][cc(128)][lane][j]
//   wsrf: w_sr [o_tile(16)][cc(128)][lane][j]
//   kkbh: k    [b][h(8)][m(1024)][d(32)]
//
// Pipeline (5 launches):
//   K1 k_prep  : weight conv + zero(v,ssg) || im2col         (1120 blocks)
//   K2 k_cx    : conv1f || xT+v, parity-interleaved          (1024 blocks)
//   K3 k_kmat2 : k GEMM + A/B0 prep                          (130 blocks)
//   K4 k_scores: q + scores, head-pair split, ssg atomicAdd  (2048 blocks)
//                (proven round-0 structure: 32 waves/CU; plain atomics,
//                 NO fences — fences caused the round-1 L2-thrash)
//   K5 k_epi   : out = A*ssg + B0                            (512 blocks)

// ---------------------------------------------------------------------------
// K1: weight conversions + zeroing + im2col.  grid = 576 + 32 + 512 = 1120.
__global__ __launch_bounds__(256) void k_prep(const float* __restrict__ wq,
                                              const float* __restrict__ wk,
                                              const float* __restrict__ wsr,
                                              const float* __restrict__ x,
                                              __bf16* __restrict__ wqf,
                                              __bf16* __restrict__ wkb,
                                              __bf16* __restrict__ wsrf,
                                              __bf16* __restrict__ Pbf,
                                              float* __restrict__ v,
                                              float* __restrict__ ssg) {
    const int bi = blockIdx.x, t = threadIdx.x;
    if (bi >= 608) {
        // ---- im2col (pure staging, no barriers) ----
        const int bid = bi - 608;
        const int b = bid >> 8, hm = (bid >> 3) & 31, ccg = bid & 7;
        const int wm = t >> 3, c8 = t & 7;
        const int mtile = (hm << 1) + (wm >> 4);
        const int ln = wm & 15;
#pragma unroll
        for (int cci = 0; cci < 4; ++cci) {
            const int c = (ccg << 5) + (cci << 3) + c8;
            const float* src = x + ((size_t)(b * 256 + c) << 14) + (hm << 9) + (wm << 2);
            bf16x8 o0, o1;
#pragma unroll
            for (int p = 0; p < 2; ++p) {
                float4 vv = *(const float4*)&src[p << 7];
                o0[p * 4 + 0] = (__bf16)vv.x; o0[p * 4 + 1] = (__bf16)vv.y;
                o0[p * 4 + 2] = (__bf16)vv.z; o0[p * 4 + 3] = (__bf16)vv.w;
            }
#pragma unroll
            for (int p = 0; p < 2; ++p) {
                float4 vv = *(const float4*)&src[(p + 2) << 7];
                o1[p * 4 + 0] = (__bf16)vv.x; o1[p * 4 + 1] = (__bf16)vv.y;
                o1[p * 4 + 2] = (__bf16)vv.z; o1[p * 4 + 3] = (__bf16)vv.w;
            }
            size_t d0 = (((((size_t)(b * 64 + mtile) << 7) + (c >> 1)) << 6) +
                         (((c & 1) << 1) << 4) + ln) << 3;
            *(bf16x8*)&Pbf[d0] = o0;
            *(bf16x8*)&Pbf[d0 + 128] = o1;
        }
        return;
    }
    if (bi >= 576) {  // zero ssg (2*16384 floats)
        int e = (bi - 576) * 256 + t;
        *(float4*)&ssg[e << 2] = make_float4(0.f, 0.f, 0.f, 0.f);
        return;
    }
    if (bi < 32) {
        if (bi == 0) { v[t] = 0.f; v[256 + t] = 0.f; }
        int tt = bi * 256 + t;
        int o = tt >> 5, chunk = tt & 31;
        float4 v0 = *(const float4*)&wq[o * 256 + (chunk << 3)];
        float4 v1 = *(const float4*)&wq[o * 256 + (chunk << 3) + 4];
        bf16x8 p;
        p[0] = (__bf16)v0.x; p[1] = (__bf16)v0.y; p[2] = (__bf16)v0.z; p[3] = (__bf16)v0.w;
        p[4] = (__bf16)v1.x; p[5] = (__bf16)v1.y; p[6] = (__bf16)v1.z; p[7] = (__bf16)v1.w;
        int cc = chunk >> 2, quad = chunk & 3;
        *(bf16x8*)&wqf[(((((o >> 4) << 3) + cc) << 6) + (quad << 4) + (o & 15)) << 3] = p;
    } else if (bi < 64) {
        int e = (bi - 32) * 256 + t;
        float4 v0 = *(const float4*)&wk[e << 3];
        float4 v1 = *(const float4*)&wk[(e << 3) + 4];
        bf16x8 p;
        p[0] = (__bf16)(v0.x * SCALE); p[1] = (__bf16)(v0.y * SCALE);
        p[2] = (__bf16)(v0.z * SCALE); p[3] = (__bf16)(v0.w * SCALE);
        p[4] = (__bf16)(v1.x * SCALE); p[5] = (__bf16)(v1.y * SCALE);
        p[6] = (__bf16)(v1.z * SCALE); p[7] = (__bf16)(v1.w * SCALE);
        *(bf16x8*)&wkb[e << 3] = p;
    } else {
        int tt = (bi - 64) * 256 + t;
        int o = tt >> 9, chunk = tt & 511;
        float4 v0 = *(const float4*)&wsr[o * 4096 + (chunk << 3)];
        float4 v1 = *(const float4*)&wsr[o * 4096 + (chunk << 3) + 4];
        bf16x8 p;
        p[0] = (__bf16)v0.x; p[1] = (__bf16)v0.y; p[2] = (__bf16)v0.z; p[3] = (__bf16)v0.w;
        p[4] = (__bf16)v1.x; p[5] = (__bf16)v1.y; p[6] = (__bf16)v1.z; p[7] = (__bf16)v1.w;
        int cc = chunk >> 2, quad = chunk & 3;
        *(bf16x8*)&wsrf[(((((o >> 4) << 7) + cc) << 6) + (quad << 4) + (o & 15)) << 3] = p;
    }
}

// ---------------------------------------------------------------------------
// K2: parity-interleaved: even blocks = conv1f (MFMA-bound), odd = xT+v (BW).
__global__ __launch_bounds__(256) void k_cx(const __bf16* __restrict__ Pbf,
                                            const __bf16* __restrict__ wsrf,
                                            const float* __restrict__ sg,
                                            const float* __restrict__ sb,
                                            const float* __restrict__ smn,
                                            const float* __restrict__ svar,
                                            __bf16* __restrict__ xrb,
                                            const float* __restrict__ x,
                                            __bf16* __restrict__ xTf,
                                            float* __restrict__ v) {
    const int t = threadIdx.x, bid0 = blockIdx.x;
    if ((bid0 & 1) == 0) {
        // ---- conv1f ----
        const int cid = bid0 >> 1;
        const int b = cid & 1, mt = (cid >> 1) & 63, og = cid >> 7;
        const int w = t >> 6, lane = t & 63, ln = lane & 15, quad = lane >> 4;
        f32x4 acc = (f32x4){0.f, 0.f, 0.f, 0.f};
        const __bf16* pa = Pbf + ((size_t)(b * 64 + mt) << 16) + (lane << 3);
        const __bf16* pbm = wsrf + ((size_t)(og * 4 + w) << 16) + (lane << 3);
#pragma unroll 8
        for (int cc = 0; cc < 128; ++cc) {
            bf16x8 af = *(const bf16x8*)&pa[cc << 9];
            bf16x8 bf = *(const bf16x8*)&pbm[cc << 9];
            acc = __builtin_amdgcn_mfma_f32_16x16x32_bf16(af, bf, acc, 0, 0, 0);
        }
        const int o = (og << 6) + (w << 4) + ln;
        float inv = sg[o] / sqrtf(svar[o] + EPSF);
        float mn = smn[o], bt = sb[o];
#pragma unroll
        for (int r = 0; r < 4; ++r) {
            int m = (mt << 4) + (quad << 2) + r;
            xrb[(((size_t)b << 10) + m) * 256 + o] = (__bf16)((acc[r] - mn) * inv + bt);
        }
    } else {
        // ---- xT + v ----
        __shared__ float ts[32 * 68];
        __shared__ float sv[256];
        const int bid = bid0 >> 1;
        const int b = bid >> 8, n0 = (bid & 255) << 6;
        const int nl = t >> 2;
        const int ch = (t & 3) << 3;
        const int n = n0 + nl;
        const int ntile = n >> 4, ln = n & 15, quad = ch >> 3;
        const int cl = t >> 3;
        const int n8 = (t & 7) << 3;
        sv[t] = 0.f;
        for (int s8 = 0; s8 < 8; ++s8) {
            const int c0 = s8 << 5;
            __syncthreads();
            {
                const float* src = &x[((size_t)(b * 256 + c0 + cl) << 14) + n0 + n8];
                float4 a0 = *(const float4*)&src[0];
                float4 a1 = *(const float4*)&src[4];
                *(float4*)&ts[cl * 68 + n8] = a0;
                *(float4*)&ts[cl * 68 + n8 + 4] = a1;
                atomicAdd(&sv[c0 + cl],
                          a0.x + a0.y + a0.z + a0.w + a1.x + a1.y + a1.z + a1.w);
            }
            __syncthreads();
            bf16x8 p;
#pragma unroll
            for (int j = 0; j < 8; ++j) p[j] = (__bf16)ts[(ch + j) * 68 + nl];
            *(bf16x8*)&xTf[(((((size_t)(b * 1024 + ntile) << 3) + s8) << 6) +
                            (quad << 4) + ln) << 3] = p;
        }
        __syncthreads();
        atomicAdd(&v[b * 256 + t], sv[t]);
    }
}

// ---------------------------------------------------------------------------
// K3: MFMA GEMM kkbh = xrb x wkb (blocks 0..127) + k_ab work (128..129).
__global__ __launch_bounds__(256) void k_kmat2(const __bf16* __restrict__ xrb,
                                               const __bf16* __restrict__ wkb,
                                               __bf16* __restrict__ kkbh,
                                               const float* __restrict__ v,
                                               const float* __restrict__ wproj,
                                               const float* __restrict__ pg,
                                               const float* __restrict__ pb,
                                               const float* __restrict__ pm,
                                               const float* __restrict__ pvar,
                                               float* __restrict__ A,
                                               float* __restrict__ B0) {
    const int t = threadIdx.x, bid = blockIdx.x;
    if (bid >= 128) {
        // ---- k_ab ----
        __shared__ float vl[256];
        int b = bid - 128;
        vl[t] = v[b * 256 + t] * (1.0f / 16384.0f);
        __syncthreads();
        const float* wr = wproj + t * 256;
        float s = 0.f;
#pragma unroll 8
        for (int c = 0; c < 256; c += 4) {
            float4 w4 = *(const float4*)&wr[c];
            s += w4.x * vl[c] + w4.y * vl[c + 1] + w4.z * vl[c + 2] + w4.w * vl[c + 3];
        }
        float inv = pg[t] / sqrtf(pvar[t] + EPSF);
        A[b * 256 + t] = s * inv;
        if (b == 0) B0[t] = pb[t] - pm[t] * inv;
        return;
    }
    const int b = bid >> 6, mt = bid & 63;
    const int w = t >> 6, lane = t & 63, ln = lane & 15, quad = lane >> 4;
    f32x4 acc[4];
#pragma unroll
    for (int ot = 0; ot < 4; ++ot) acc[ot] = (f32x4){0.f, 0.f, 0.f, 0.f};
    const __bf16* pa = xrb + ((((size_t)b << 10) + (mt << 4) + ln) << 8) + (quad << 3);
    const __bf16* pbm = wkb + (((w << 6) + ln) << 8) + (quad << 3);
#pragma unroll
    for (int cc = 0; cc < 8; ++cc) {
        const int cb = cc << 5;
        bf16x8 af = *(const bf16x8*)&pa[cb];
        bf16x8 bfr[4];
#pragma unroll
        for (int ot = 0; ot < 4; ++ot) bfr[ot] = *(const bf16x8*)&pbm[(ot << 12) + cb];
#pragma unroll
        for (int ot = 0; ot < 4; ++ot)
            acc[ot] = __builtin_amdgcn_mfma_f32_16x16x32_bf16(af, bfr[ot], acc[ot], 0, 0, 0);
    }
#pragma unroll
    for (int ot = 0; ot < 4; ++ot)
#pragma unroll
        for (int r = 0; r < 4; ++r) {
            int m = (mt << 4) + (quad << 2) + r;
            int h = (w << 1) + (ot >> 1);
            int d = ((ot & 1) << 4) + ln;
            kkbh[(((size_t)(b * 8 + h)) << 15) + (m << 5) + d] = (__bf16)acc[ot][r];
        }
}

// ---------------------------------------------------------------------------
// K4: head-pair split (round-0 proven).  grid = b(2) x nchunk(256) x hp(4).
// q phase: wave w = ntile w, 64 o (the pair's heads).  score phase: wave w =
// m-quarter.  Result: atomicAdd of (max_h0 + max_h1) into ssg[b][n].
__global__ __launch_bounds__(256) void k_scores2(const __bf16* __restrict__ xTf,
                                                 const __bf16* __restrict__ wqf,
                                                 const __bf16* __restrict__ kkbh,
                                                 float* __restrict__ ssg) {
    __shared__ __align__(16) __bf16 qs[64 * 72];
    __shared__ float smax[512];  // [w][hl][n64]
    const int t = threadIdx.x;
    const int w = t >> 6;
    const int lane = t & 63;
    const int ln = lane & 15;
    const int quad = lane >> 4;
    const int bx = blockIdx.x;
    const int hp = bx & 3;
    const int n0 = ((bx >> 2) & 255) << 6;
    const int b = bx >> 10;

    // ---------------- q phase: wave w computes q[ntile w][64 o of pair]
    f32x4 acc[4];
#pragma unroll
    for (int ot = 0; ot < 4; ++ot) acc[ot] = (f32x4){0.f, 0.f, 0.f, 0.f};
    const __bf16* pa = xTf + ((size_t)(b * 1024 + (n0 >> 4) + w) << 12) + (lane << 3);
    const __bf16* pbm = wqf + ((size_t)(hp << 2) << 12) + (lane << 3);
#pragma unroll 2
    for (int cc = 0; cc < 8; ++cc) {
        const int cb = cc << 9;
        bf16x8 af = *(const bf16x8*)&pa[cb];
        bf16x8 bfr[4];
#pragma unroll
        for (int ot = 0; ot < 4; ++ot) bfr[ot] = *(const bf16x8*)&pbm[(ot << 12) + cb];
#pragma unroll
        for (int ot = 0; ot < 4; ++ot)
            acc[ot] = __builtin_amdgcn_mfma_f32_16x16x32_bf16(af, bfr[ot], acc[ot], 0, 0, 0);
    }
#pragma unroll
    for (int ot = 0; ot < 4; ++ot)
#pragma unroll
        for (int r = 0; r < 4; ++r)
            qs[((w << 4) + (quad << 2) + r) * 72 + (ot << 4) + ln] = (__bf16)acc[ot][r];
    __syncthreads();

    // ---------------- score phase: wave w = m range [w*256, w*256+256)
    const f32x4 zf = {0.f, 0.f, 0.f, 0.f};
#pragma unroll
    for (int hl = 0; hl < 2; ++hl) {
        const int h = (hp << 1) + hl;
        bf16x8 qb[4];
#pragma unroll
        for (int nt = 0; nt < 4; ++nt)
            qb[nt] = *(const bf16x8*)&qs[((nt << 4) + ln) * 72 + (hl << 5) + (quad << 3)];
        const __bf16* kb_base = kkbh + ((size_t)(b * 8 + h) << 15) + (ln << 5) + (quad << 3);
        bf16x8 kb[16];
#pragma unroll
        for (int i = 0; i < 16; ++i)
            kb[i] = *(const bf16x8*)&kb_base[((w << 8) + (i << 4)) << 5];
        float rmx[4] = {-INFINITY, -INFINITY, -INFINITY, -INFINITY};
        __builtin_amdgcn_s_setprio(1);
#pragma unroll
        for (int i = 0; i < 16; ++i)
#pragma unroll
            for (int nt = 0; nt < 4; ++nt) {
                f32x4 d = __builtin_amdgcn_mfma_f32_16x16x32_bf16(kb[i], qb[nt], zf, 0, 0, 0);
                float t1 = fmaxf(fmaxf(d[0], d[1]), d[2]);       // -> v_max3
                rmx[nt] = fmaxf(fmaxf(t1, d[3]), rmx[nt]);       // -> v_max3
            }
        __builtin_amdgcn_s_setprio(0);
#pragma unroll
        for (int nt = 0; nt < 4; ++nt) {
            rmx[nt] = fmaxf(rmx[nt], __shfl_xor(rmx[nt], 16, 64));
            rmx[nt] = fmaxf(rmx[nt], __shfl_xor(rmx[nt], 32, 64));
        }
        if (lane < 16) {
#pragma unroll
            for (int nt = 0; nt < 4; ++nt)
                smax[(w << 7) + (hl << 6) + (nt << 4) + lane] = rmx[nt];
        }
    }
    __syncthreads();
    if (t < 64) {
        float s0 = fmaxf(fmaxf(smax[t], smax[128 + t]), fmaxf(smax[256 + t], smax[384 + t]));
        float s1 = fmaxf(fmaxf(smax[64 + t], smax[192 + t]),
                         fmaxf(smax[320 + t], smax[448 + t]));
        atomicAdd(&ssg[(b << 14) + n0 + t], s0 + s1);
    }
}

// ---------------------------------------------------------------------------
// K5: out[b][c][n] = A[b][c]*ssg[b][n] + B0[c].  grid = 512.
__global__ __launch_bounds__(256) void k_epi(const float* __restrict__ ssg,
                                             const float* __restrict__ A,
                                             const float* __restrict__ B0,
                                             float* __restrict__ out) {
    __shared__ float ss[64], sA[256], sB[256];
    const int t = threadIdx.x, bid = blockIdx.x;
    const int b = bid >> 8, n0 = (bid & 255) << 6;
    if (t < 64) ss[t] = ssg[(b << 14) + n0 + t];
    sA[t] = A[b * 256 + t];
    sB[t] = B0[t];
    __syncthreads();
#pragma unroll
    for (int i = 0; i < 16; ++i) {
        int e = t + (i << 8);
        int c = e >> 4, n4 = (e & 15) << 2;
        float4 s4 = *(const float4*)&ss[n4];
        float a = sA[c], bb = sB[c];
        float4 o4 = make_float4(fmaf(a, s4.x, bb), fmaf(a, s4.y, bb),
                                fmaf(a, s4.z, bb), fmaf(a, s4.w, bb));
        *(float4*)&out[((size_t)(b * 256 + c) << 14) + n0 + n4] = o4;
    }
}

// ---------------------------------------------------------------------------
extern "C" void kernel_launch(void* const* d_in, const int* in_sizes, int n_in,
                              void* d_out, int out_size, void* d_ws, size_t ws_size,
                              hipStream_t stream) {
    const float* x    = (const float*)d_in[0];
    const float* wq   = (const float*)d_in[1];
    const float* wk   = (const float*)d_in[2];
    const float* wsr  = (const float*)d_in[3];
    const float* sg   = (const float*)d_in[4];
    const float* sb   = (const float*)d_in[5];
    const float* smn  = (const float*)d_in[6];
    const float* svr  = (const float*)d_in[7];
    const float* wproj= (const float*)d_in[8];
    const float* pg   = (const float*)d_in[9];
    const float* pb   = (const float*)d_in[10];
    const float* pm   = (const float*)d_in[11];
    const float* pvr  = (const float*)d_in[12];
    float* out = (float*)d_out;

    char* W = (char*)d_ws;
    float*  w_v   = (float*) (W + 0);          // 512 f
    float*  w_A   = (float*) (W + 4096);       // 512 f
    float*  w_B0  = (float*) (W + 8192);       // 256 f
    float*  w_ssg = (float*) (W + 12288);      // 128 KB (2*16384 f)
    __bf16* w_wqf = (__bf16*)(W + 147456);     // 128 KB
    __bf16* w_wkb = (__bf16*)(W + 278528);     // 128 KB
    __bf16* w_wsrf= (__bf16*)(W + 409600);     // 2 MB
    __bf16* w_xrb = (__bf16*)(W + 2506752);    // 512 KB
    __bf16* w_kkbh= (__bf16*)(W + 3031040);    // 1 MB
    __bf16* w_Pbf = (__bf16*)(W + 4079616);    // 16.8 MB
    __bf16* w_xTf = (__bf16*)(W + 20856832);   // 16.8 MB

    k_prep<<<1120, 256, 0, stream>>>(wq, wk, wsr, x, w_wqf, w_wkb, w_wsrf, w_Pbf,
                                     w_v, w_ssg);
    k_cx<<<1024, 256, 0, stream>>>(w_Pbf, w_wsrf, sg, sb, smn, svr, w_xrb,
                                   x, w_xTf, w_v);
    k_kmat2<<<130, 256, 0, stream>>>(w_xrb, w_wkb, w_kkbh, w_v, wproj, pg, pb, pm, pvr,
                                     w_A, w_B0);
    k_scores2<<<2048, 256, 0, stream>>>(w_xTf, w_wqf, w_kkbh, w_ssg);
    k_epi<<<512, 256, 0, stream>>>(w_ssg, w_A, w_B0, out);
}